// Round 2
// baseline (1639.243 us; speedup 1.0000x reference)
//
#include <hip/hip_runtime.h>
#include <hip/hip_bf16.h>
#include <math.h>

#define HID 256
#define MOTIF 640
#define PEAK 1000
#define NPEAKS 128   // B * NUM_PEAKS
#define DEPTHN 7
#define PROFK 75
#define FINLEN 492
#define PROFLEN 418

typedef unsigned short u16;
typedef unsigned int u32;
typedef _Float16 f16x8 __attribute__((ext_vector_type(8)));
typedef float f32x16 __attribute__((ext_vector_type(16)));

__device__ __forceinline__ u16 f2h(float f) {
    _Float16 h = (_Float16)f; u16 b; __builtin_memcpy(&b, &h, 2); return b;
}
__device__ __forceinline__ float h2f(u16 b) {
    _Float16 h; __builtin_memcpy(&h, &b, 2); return (float)h;
}
__device__ __forceinline__ float hlo(u32 u) { return h2f((u16)(u & 0xffff)); }
__device__ __forceinline__ float hhi(u32 u) { return h2f((u16)(u >> 16)); }
__device__ __forceinline__ u32 pk2h(float a, float b) {
    return (u32)f2h(a) | ((u32)f2h(b) << 16);
}
__device__ __forceinline__ f16x8 cvt8(float4 a, float4 b) {
    f16x8 r;
    r[0] = (_Float16)a.x; r[1] = (_Float16)a.y;
    r[2] = (_Float16)a.z; r[3] = (_Float16)a.w;
    r[4] = (_Float16)b.x; r[5] = (_Float16)b.y;
    r[6] = (_Float16)b.z; r[7] = (_Float16)b.w;
    return r;
}

// ---------------------------------------------------------------------------
// Weight repack, ALL dilated layers at once: w (DEPTH,HID,HID,3) fp32 ->
// fp16 [layer][k*16+ci16][c][16]. Also zeroes the 128-float atpm partials.
// grid (768, 7), block 256.
// ---------------------------------------------------------------------------
__global__ __launch_bounds__(256) void conv_wdil_all(const float* __restrict__ w,
                                                     u16* __restrict__ wf,
                                                     float* __restrict__ zp) {
    const int layer = blockIdx.y;
    int i = blockIdx.x * 256 + threadIdx.x;          // covers 3*256*256 exactly
    if (layer == 0 && i < NPEAKS) zp[i] = 0.f;
    const float* wl = w + (size_t)layer * HID * HID * 3;
    u16* wfl = wf + (size_t)layer * (3 * HID * HID);
    int cil = i & 15; int j = i >> 4;
    int c = j & 255; j >>= 8;                        // j = k*16 + ci16
    int ci16 = j & 15; int k = j >> 4;
    wfl[i] = f2h(wl[((size_t)c * HID + ci16 * 16 + cil) * 3 + k]);
}

// wproj (HID, MOTIF, 1) fp32 -> fp16 [m16][c][16]
__global__ __launch_bounds__(256) void conv_wproj(const float* __restrict__ w,
                                                  u16* __restrict__ wf) {
    int i = blockIdx.x * 256 + threadIdx.x;
    if (i >= MOTIF * HID) return;
    int ml = i & 15;
    int c = (i >> 4) & 255;
    int m16 = i >> 12;
    wf[i] = f2h(w[(size_t)c * MOTIF + m16 * 16 + ml]);
}

// ---------------------------------------------------------------------------
// MFMA GEMM, BARRIER-FREE direct-streaming variant:
//   dst[n][t][c] = act( sum_{k,ci} W[k][c][ci]*src[n][t+k*DIL][ci] + bias[c] )
//   (+ residual src[n][t+DIL][c] when RESID; + fused atpm partial when ATPM)
// Block 256 thr = 4 waves; tile 128c x 128t (wave 64c x 64t, acc[2][2]).
// No LDS, no __syncthreads in the main loop: the B-operand MFMA fragment
// (8 consecutive ci at one t) is CONTIGUOUS in the [t][ci] activation layout,
// so each lane loads it with one global_load_dwordx4. A-frags (weights) are
// 1KB-coalesced per wave and L2-resident. Loads interleave 1:1 with MFMA in a
// fully-unrolled body -> compiler pipelines via counted vmcnt with no barrier
// drains (the m233 2-phase stall is structurally removed). Tap/row reuse is
// served by L1 (consecutive ktiles stream adjacent 32B chunks of each 512B row;
// the c-partner wave reads identical rows).
// Lanes with t >= out_len clamp their row to out_len-1 (safe, discarded).
// ---------------------------------------------------------------------------
template<int TAPS, int KCI, int DIL, bool SRCF32, bool RESID, bool ATPM>
__global__ __launch_bounds__(256, 3) void mfma_gemm(
    const void* __restrict__ src, int in_len, int in_stride,
    const u16* __restrict__ wf, const float* __restrict__ bias,
    u16* __restrict__ dst, int out_len,
    const float* __restrict__ watpm, float* part)
{
    __shared__ float aw[4];                          // ATPM reduction only
    const int tid = threadIdx.x;
    const int wave = tid >> 6, lane = tid & 63;
    const int col = lane & 31, half = lane >> 5;
    const int cg = wave & 1, tg = wave >> 1;
    const int t0 = blockIdx.x * 128;
    const int c0 = blockIdx.y * 128;
    const int n  = blockIdx.z;

    const float* snf = (const float*)src + (size_t)n * in_len * in_stride;
    const u16*   snh = (const u16*)src + (size_t)n * in_len * in_stride;

    f32x16 acc[2][2];
    #pragma unroll
    for (int cs = 0; cs < 2; ++cs)
        #pragma unroll
        for (int ts = 0; ts < 2; ++ts)
            #pragma unroll
            for (int q = 0; q < 16; ++q) acc[cs][ts][q] = 0.f;

    // clamped per-lane row index for each ts (results for t>=out_len discarded)
    int trc[2];
    {
        const int tb = t0 + tg * 64 + col;
        trc[0] = tb      < out_len ? tb      : out_len - 1;
        trc[1] = tb + 32 < out_len ? tb + 32 : out_len - 1;
    }
    // per-lane weight base: frag for (ktile, cs) at wfp + (ktile*256 + cs*32)*16
    const u16* wfp = wf + (size_t)(c0 + cg * 64 + col) * 16 + half * 8;

    #pragma unroll
    for (int k = 0; k < TAPS; ++k) {
        // per-(ts,k) row base offsets (in elements)
        size_t bb0 = (size_t)(trc[0] + k * DIL) * in_stride + half * 8;
        size_t bb1 = (size_t)(trc[1] + k * DIL) * in_stride + half * 8;
        #pragma unroll
        for (int kt = 0; kt < KCI / 16; ++kt) {
            const int ktile = k * (KCI / 16) + kt;
            f16x8 bfv[2];
            if (SRCF32) {
                const float4* p0 = (const float4*)(snf + bb0 + kt * 16);
                const float4* p1 = (const float4*)(snf + bb1 + kt * 16);
                bfv[0] = cvt8(p0[0], p0[1]);
                bfv[1] = cvt8(p1[0], p1[1]);
            } else {
                bfv[0] = *(const f16x8*)(snh + bb0 + kt * 16);
                bfv[1] = *(const f16x8*)(snh + bb1 + kt * 16);
            }
            #pragma unroll
            for (int cs = 0; cs < 2; ++cs) {
                const f16x8 af = *(const f16x8*)(wfp + ((size_t)ktile * 256 + cs * 32) * 16);
                acc[cs][0] = __builtin_amdgcn_mfma_f32_32x32x16_f16(af, bfv[0], acc[cs][0], 0, 0, 0);
                acc[cs][1] = __builtin_amdgcn_mfma_f32_32x32x16_f16(af, bfv[1], acc[cs][1], 0, 0, 0);
            }
        }
    }

    // Epilogue. C/D: c_local = (r&3) + 8*(r>>2) + 4*half, t = lane&31.
    float apart = 0.f;
    #pragma unroll
    for (int ts = 0; ts < 2; ++ts) {
        const int t = t0 + tg * 64 + ts * 32 + col;
        if (t >= out_len) continue;
        const float* resf = snf + (size_t)(t + DIL) * in_stride;
        const u16*   resh = snh + (size_t)(t + DIL) * in_stride;
        u16* oh = dst + ((size_t)n * out_len + t) * HID;
        #pragma unroll
        for (int cs = 0; cs < 2; ++cs) {
            #pragma unroll
            for (int g = 0; g < 4; ++g) {
                const int c = c0 + cg * 64 + cs * 32 + g * 8 + half * 4;
                float4 bv = *(const float4*)(bias + c);
                float v0 = acc[cs][ts][g * 4 + 0] + bv.x;
                float v1 = acc[cs][ts][g * 4 + 1] + bv.y;
                float v2 = acc[cs][ts][g * 4 + 2] + bv.z;
                float v3 = acc[cs][ts][g * 4 + 3] + bv.w;
                if (RESID) {
                    if (SRCF32) {
                        float4 r = *(const float4*)(resf + c);
                        v0 = fmaxf(v0, 0.f) + r.x;
                        v1 = fmaxf(v1, 0.f) + r.y;
                        v2 = fmaxf(v2, 0.f) + r.z;
                        v3 = fmaxf(v3, 0.f) + r.w;
                    } else {
                        uint2 r = *(const uint2*)(resh + c);
                        v0 = fmaxf(v0, 0.f) + hlo(r.x);
                        v1 = fmaxf(v1, 0.f) + hhi(r.x);
                        v2 = fmaxf(v2, 0.f) + hlo(r.y);
                        v3 = fmaxf(v3, 0.f) + hhi(r.y);
                    }
                }
                if (ATPM) {
                    float4 wv = *(const float4*)(watpm + c);
                    apart += v0 * wv.x + v1 * wv.y + v2 * wv.z + v3 * wv.w;
                }
                uint2 o; o.x = pk2h(v0, v1); o.y = pk2h(v2, v3);
                *(uint2*)(oh + c) = o;
            }
        }
    }
    if (ATPM) {
        #pragma unroll
        for (int off = 32; off; off >>= 1) apart += __shfl_down(apart, off, 64);
        if (lane == 0) aw[wave] = apart;
        __syncthreads();
        if (tid == 0) atomicAdd(part + n, aw[0] + aw[1] + aw[2] + aw[3]);
    }
}

// ---------------------------------------------------------------------------
// atpm finalize: out[n] = softplus(part[n]/492 + b)
// ---------------------------------------------------------------------------
__global__ void atpm_fin(const float* __restrict__ part,
                         const float* __restrict__ batpm, float* __restrict__ out) {
    int i = threadIdx.x;   // 128
    float tot = part[i] / (float)FINLEN + batpm[0];
    out[i] = fmaxf(tot, 0.f) + log1pf(expf(-fabsf(tot)));
}

// ---------------------------------------------------------------------------
// profile head, sliding-window: out[n][t] = softplus( sum_{ci,k} w[ci][k] h[n][t+k][ci] + b )
// h is fp16 [n][t][256]. Block covers 128 t; thread owns 4 t's x 8-ci subrange.
// grid (4, 128), block 256.
// ---------------------------------------------------------------------------
__global__ __launch_bounds__(256) void prof_kernel(
    const u16* __restrict__ h, const float* __restrict__ wprof,
    const float* __restrict__ bprof, float* __restrict__ out)
{
    __shared__ __attribute__((aligned(16))) float hs[64 * 204];  // 52.2 KB
    __shared__ float red[128 * 8];                               // 4 KB
    const int tid = threadIdx.x;
    const int wave = tid >> 6, lane = tid & 63;
    const int ts = lane & 31, hw = lane >> 5;
    const int cig = wave * 2 + hw;           // 0..7
    const int n = blockIdx.y, t0 = blockIdx.x * 128;
    const u16* hn = h + (size_t)n * FINLEN * HID;
    float acc[4] = {0.f, 0.f, 0.f, 0.f};

    for (int ci0 = 0; ci0 < HID; ci0 += 64) {
        __syncthreads();
        {   // stage rows [t0, t0+203] (clamped) for ci-window, transposed
            const int ci = tid & 63, rg = tid >> 6;
            for (int base = 0; base < 204; base += 16) {
                const int r0 = base + rg * 4;
                if (r0 >= 204) continue;
                float4 v;
                float* vp = (float*)&v;
                #pragma unroll
                for (int j = 0; j < 4; ++j) {
                    int g = t0 + r0 + j; if (g > FINLEN - 1) g = FINLEN - 1;
                    vp[j] = h2f(hn[(size_t)g * HID + ci0 + ci]);
                }
                *(float4*)&hs[ci * 204 + r0] = v;
            }
        }
        __syncthreads();
        for (int ci = 0; ci < 8; ++ci) {
            const int cia = cig * 8 + ci;
            const float4* hrow = (const float4*)&hs[cia * 204];
            const float* wrow = wprof + (size_t)(ci0 + cia) * PROFK;
            float wqf[84];
            #pragma unroll
            for (int q = 0; q < 3; ++q) wqf[q] = 0.f;
            #pragma unroll
            for (int q = 78; q < 84; ++q) wqf[q] = 0.f;
            #pragma unroll
            for (int k = 0; k < PROFK; ++k) wqf[k + 3] = wrow[k];
            #pragma unroll
            for (int m = 0; m < 20; ++m) {
                float4 h4 = hrow[ts + m];
                const float* hp = (const float*)&h4;
                #pragma unroll
                for (int j = 0; j < 4; ++j) {
                    #pragma unroll
                    for (int a = 0; a < 4; ++a) {
                        acc[a] += wqf[4 * m + j - a + 3] * hp[j];
                    }
                }
            }
        }
    }
    #pragma unroll
    for (int a = 0; a < 4; ++a) red[(ts * 4 + a) * 8 + cig] = acc[a];
    __syncthreads();
    if (tid < 128) {
        float s = 0.f;
        #pragma unroll
        for (int c8 = 0; c8 < 8; ++c8) s += red[tid * 8 + c8];
        const int t = t0 + tid;
        if (t < PROFLEN) {
            float v = s + bprof[0];
            out[(size_t)n * PROFLEN + t] = fmaxf(v, 0.f) + log1pf(expf(-fabsf(v)));
        }
    }
}

// ---------------------------------------------------------------------------
extern "C" void kernel_launch(void* const* d_in, const int* in_sizes, int n_in,
                              void* d_out, int out_size, void* d_ws, size_t ws_size,
                              hipStream_t stream) {
    const float* x     = (const float*)d_in[0];
    const float* wproj = (const float*)d_in[4];
    const float* bproj = (const float*)d_in[5];
    const float* wdil  = (const float*)d_in[6];
    const float* bdil  = (const float*)d_in[7];
    const float* wprof = (const float*)d_in[8];
    const float* bprof = (const float*)d_in[9];
    const float* watpm = (const float*)d_in[10];
    const float* batpm = (const float*)d_in[11];
    float* outAtpm = (float*)d_out;
    float* outProf = outAtpm + NPEAKS;

    // ws layout (~134.2 MB of the >=262 MB workspace), all fp16 activations:
    //   hA @ 0          : 65,536,000 B
    //   hB @ 65536000   : 65,536,000 B
    //   wpf @ 131072000 : 327,680 B (proj weights fp16 frag-ordered)
    //   wslot @ 131399680 : 7 x 393,216 B (all dilated-layer weights, repacked upfront)
    //   part @ 134152192 : 512 B (atpm partials)
    char* ws = (char*)d_ws;
    u16* hA    = (u16*)ws;
    u16* hB    = (u16*)(ws + 65536000);
    u16* wpf   = (u16*)(ws + 131072000);
    u16* wslot = (u16*)(ws + 131399680);
    float* part = (float*)(ws + 134152192);

    // all weight repacks upfront (no mid-stream launches, no rotating-buffer dep)
    conv_wproj<<<(MOTIF * HID + 255) / 256, 256, 0, stream>>>(wproj, wpf);
    conv_wdil_all<<<dim3(768, DEPTHN), 256, 0, stream>>>(wdil, wslot, part);

    // projection: x fp32 (K=640) -> hA fp16 [n][t][c]
    mfma_gemm<1, MOTIF, 0, true, false, false><<<dim3(8, 2, NPEAKS), 256, 0, stream>>>(
        x, PEAK, MOTIF, wpf, bproj, hA, PEAK, nullptr, nullptr);

    #define LAYER(i, DIL, SRC, DST, INL, OUTL, TT)                                           \
        mfma_gemm<3, HID, DIL, false, true, false><<<dim3(TT, 2, NPEAKS), 256, 0, stream>>>( \
            SRC, INL, HID, wslot + (size_t)(i) * (3 * HID * HID),                            \
            bdil + (size_t)(i) * HID, DST, OUTL, nullptr, nullptr);
    LAYER(0,   2, hA, hB, 1000, 996, 8)
    LAYER(1,   4, hB, hA,  996, 988, 8)
    LAYER(2,   8, hA, hB,  988, 972, 8)
    LAYER(3,  16, hB, hA,  972, 940, 8)
    LAYER(4,  32, hA, hB,  940, 876, 7)
    LAYER(5,  64, hB, hA,  876, 748, 6)
    #undef LAYER
    // layer 6 with fused atpm partial accumulation (part zeroed in the repack)
    mfma_gemm<3, HID, 128, false, true, true><<<dim3(4, 2, NPEAKS), 256, 0, stream>>>(
        hA, 748, HID, wslot + (size_t)6 * (3 * HID * HID), bdil + (size_t)6 * HID,
        hB, 492, watpm, part);

    atpm_fin<<<1, 128, 0, stream>>>(part, batpm, outAtpm);
    prof_kernel<<<dim3(4, NPEAKS), 256, 0, stream>>>(hB, wprof, bprof, outProf);
}

// Round 3
// 1155.421 us; speedup vs baseline: 1.4187x; 1.4187x over previous
//
#include <hip/hip_runtime.h>
#include <hip/hip_bf16.h>
#include <math.h>

#define HID 256
#define MOTIF 640
#define PEAK 1000
#define NPEAKS 128   // B * NUM_PEAKS
#define DEPTHN 7
#define PROFK 75
#define FINLEN 492
#define PROFLEN 418

typedef unsigned short u16;
typedef unsigned int u32;
typedef _Float16 f16x8 __attribute__((ext_vector_type(8)));
typedef float f32x16 __attribute__((ext_vector_type(16)));

__device__ __forceinline__ u16 f2h(float f) {
    _Float16 h = (_Float16)f; u16 b; __builtin_memcpy(&b, &h, 2); return b;
}
__device__ __forceinline__ float h2f(u16 b) {
    _Float16 h; __builtin_memcpy(&h, &b, 2); return (float)h;
}
__device__ __forceinline__ float hlo(u32 u) { return h2f((u16)(u & 0xffff)); }
__device__ __forceinline__ float hhi(u32 u) { return h2f((u16)(u >> 16)); }
__device__ __forceinline__ u32 pk2h(float a, float b) {
    return (u32)f2h(a) | ((u32)f2h(b) << 16);
}

// async global->LDS, 16B per lane. HW dest = first-lane base + lane*16 (m104).
__device__ __forceinline__ void gll16(const void* g, void* l) {
    __builtin_amdgcn_global_load_lds(
        (const __attribute__((address_space(1))) void*)g,
        (__attribute__((address_space(3))) void*)l, 16, 0, 0);
}

// ---------------------------------------------------------------------------
// Weight repack, ALL dilated layers at once: w (DEPTH,HID,HID,3) fp32 ->
// fp16 [layer][k*16+ci16][c][16]. Also zeroes the 128-float atpm partials.
// grid (768, 7), block 256.
// ---------------------------------------------------------------------------
__global__ __launch_bounds__(256) void conv_wdil_all(const float* __restrict__ w,
                                                     u16* __restrict__ wf,
                                                     float* __restrict__ zp) {
    const int layer = blockIdx.y;
    int i = blockIdx.x * 256 + threadIdx.x;          // covers 3*256*256 exactly
    if (layer == 0 && i < NPEAKS) zp[i] = 0.f;
    const float* wl = w + (size_t)layer * HID * HID * 3;
    u16* wfl = wf + (size_t)layer * (3 * HID * HID);
    int cil = i & 15; int j = i >> 4;
    int c = j & 255; j >>= 8;                        // j = k*16 + ci16
    int ci16 = j & 15; int k = j >> 4;
    wfl[i] = f2h(wl[((size_t)c * HID + ci16 * 16 + cil) * 3 + k]);
}

// wproj (HID, MOTIF, 1) fp32 -> fp16 [m16][c][16]
__global__ __launch_bounds__(256) void conv_wproj(const float* __restrict__ w,
                                                  u16* __restrict__ wf) {
    int i = blockIdx.x * 256 + threadIdx.x;
    if (i >= MOTIF * HID) return;
    int ml = i & 15;
    int c = (i >> 4) & 255;
    int m16 = i >> 12;
    wf[i] = f2h(w[(size_t)c * MOTIF + m16 * 16 + ml]);
}

// ---------------------------------------------------------------------------
// MFMA GEMM, pipelined T3+T4 (counted-vmcnt, 2-deep prefetch, raw barriers):
//   dst[n][t][c] = act( sum_{k,ci} W[k][c][ci]*src[n][t+k*DIL][ci] + bias[c] )
//   (+ residual src[n][t+DIL][c] when RESID; + fused atpm partial when ATPM)
// Block 256 thr = 4 waves; tile 128c x 128t (wave 64c x 64t, acc[2][2]).
// BOTH operands are staged to LDS (A weights + B activations) so the compute
// phase is pure ds_read+MFMA -> no vmem in compute -> counted vmcnt(NIF) keeps
// the next chunk's global_load_lds in flight across barriers (vmcnt is
// in-order, so any vmem consumer inside compute would force a drain).
// Per-chunk schedule:  vmcnt(NIF); s_barrier; compute(buf c&1); s_barrier;
//                      stage(chunk c+2 -> buf c&1)
// Uniform gll issue count per wave via lane clamping + 64-slot LDS pad.
// B LDS layout: [row][GR slots] with slot ^= (row & (GR-1)) swizzle, applied
// on the pre-swizzled GLOBAL source (linear LDS dest) and on the ds_read.
// ---------------------------------------------------------------------------
template<int TAPS, int KCI, int CCI, int DIL, bool SRCF32, bool RESID, bool ATPM>
__global__ __launch_bounds__(256, 3) void mfma_gemm(
    const void* __restrict__ src, int in_len, int in_stride,
    const u16* __restrict__ wf, const float* __restrict__ bias,
    u16* __restrict__ dst, int out_len,
    const float* __restrict__ watpm, float* part)
{
    constexpr int R    = 128 + (TAPS - 1) * DIL;   // union staged rows
    constexpr int GR   = CCI / 8;                  // 16B ci-groups per row
    constexpr int SUBS = CCI / 16;                 // ci16 subtiles per chunk
    constexpr int KTC  = TAPS * SUBS;              // ktiles per chunk
    constexpr int NC   = KCI / CCI;                // chunks
    constexpr int ASLOTS = KTC * 256;              // A 16B slots per chunk
    constexpr int AIT  = KTC;                      // = ASLOTS/256 (exact)
    constexpr int BSLOTS = R * GR;
    constexpr int BIT  = (BSLOTS + 255) / 256;
    constexpr int NIF  = SRCF32 ? AIT : (AIT + BIT);  // gll in flight / chunk

    __shared__ __attribute__((aligned(16))) u16 As[2][ASLOTS * 8];
    __shared__ __attribute__((aligned(16))) u16 Bs[2][(BSLOTS + 64) * 8];
    __shared__ float aw[4];
    const int tid = threadIdx.x;
    const int wave = tid >> 6, lane = tid & 63;
    const int col = lane & 31, half = lane >> 5;
    const int cg = wave & 1, tg = wave >> 1;
    const int t0 = blockIdx.x * 128;
    const int c0 = blockIdx.y * 128;
    const int n  = blockIdx.z;

    const float* snf = (const float*)src + (size_t)n * in_len * in_stride;
    const u16*   snh = (const u16*)src + (size_t)n * in_len * in_stride;

    f32x16 acc[2][2];
    #pragma unroll
    for (int cs = 0; cs < 2; ++cs)
        #pragma unroll
        for (int ts = 0; ts < 2; ++ts)
            #pragma unroll
            for (int q = 0; q < 16; ++q) acc[cs][ts][q] = 0.f;

    auto stageA = [&](int cc, int b) {
        const int kt0 = (cc * CCI) >> 4;
        #pragma unroll
        for (int it = 0; it < AIT; ++it) {
            const int s = it * 256 + tid;            // < ASLOTS always (exact)
            const int ktl = s >> 8;
            const int c = (s & 255) >> 1, hf = s & 1;
            const int k = ktl / SUBS, sub = ktl % SUBS;
            const int ktg = k * (KCI / 16) + kt0 + sub;
            gll16(wf + (size_t)(ktg * 256 + c0 + c) * 16 + hf * 8,
                  &As[b][(size_t)s * 8]);
        }
    };
    auto stageB = [&](int cc, int b) {
        const int ci0 = cc * CCI;
        #pragma unroll
        for (int it = 0; it < BIT; ++it) {
            int s = it * 256 + tid;
            if (s >= BSLOTS) s = BSLOTS - 1;         // uniform issue; pad absorbs
            const int r = s / GR, ch = s % GR;
            int g = t0 + r; if (g > in_len - 1) g = in_len - 1;
            const int chs = ch ^ (r & (GR - 1));     // source pre-swizzle
            if (SRCF32) {
                const float* p = snf + (size_t)g * in_stride + ci0 + chs * 8;
                float4 a = *(const float4*)p;
                float4 bq = *(const float4*)(p + 4);
                uint4 o;
                o.x = pk2h(a.x, a.y); o.y = pk2h(a.z, a.w);
                o.z = pk2h(bq.x, bq.y); o.w = pk2h(bq.z, bq.w);
                *(uint4*)&Bs[b][(size_t)s * 8] = o;
            } else {
                gll16(snh + (size_t)g * in_stride + ci0 + chs * 8,
                      &Bs[b][(size_t)s * 8]);
            }
        }
    };
    auto compute = [&](int b) {
        #pragma unroll
        for (int k = 0; k < TAPS; ++k) {
            #pragma unroll
            for (int sub = 0; sub < SUBS; ++sub) {
                const int ktl = k * SUBS + sub;
                f16x8 bf[2];
                #pragma unroll
                for (int ts = 0; ts < 2; ++ts) {
                    const int row = tg * 64 + ts * 32 + col + k * DIL;
                    const int sl = row * GR + ((sub * 2 + half) ^ (row & (GR - 1)));
                    bf[ts] = *reinterpret_cast<const f16x8*>(&Bs[b][(size_t)sl * 8]);
                }
                #pragma unroll
                for (int cs = 0; cs < 2; ++cs) {
                    const f16x8 af = *reinterpret_cast<const f16x8*>(
                        &As[b][(size_t)(ktl * 256 + (cg * 64 + cs * 32 + col) * 2 + half) * 8]);
                    acc[cs][0] = __builtin_amdgcn_mfma_f32_32x32x16_f16(af, bf[0], acc[cs][0], 0, 0, 0);
                    acc[cs][1] = __builtin_amdgcn_mfma_f32_32x32x16_f16(af, bf[1], acc[cs][1], 0, 0, 0);
                }
            }
        }
    };

    // prologue: 2-deep prefetch. SRCF32 orders B (reg loads) before A (gll) so
    // the compiler's waits on B's f32 loads don't force A's gll to drain.
    if (SRCF32) { stageB(0, 0); stageA(0, 0); stageB(1, 1); stageA(1, 1); }
    else        { stageA(0, 0); stageB(0, 0); stageA(1, 1); stageB(1, 1); }

    #pragma unroll
    for (int c = 0; c < NC; ++c) {
        if (SRCF32) asm volatile("s_waitcnt lgkmcnt(0)" ::: "memory");
        if (c + 1 < NC) asm volatile("s_waitcnt vmcnt(%0)" :: "i"(NIF) : "memory");
        else            asm volatile("s_waitcnt vmcnt(0)" ::: "memory");
        __builtin_amdgcn_s_barrier();
        asm volatile("" ::: "memory");      // fence: ds_reads stay after barrier
        compute(c & 1);
        asm volatile("" ::: "memory");      // fence: ds_reads stay before barrier
        __builtin_amdgcn_s_barrier();
        asm volatile("" ::: "memory");
        if (c + 2 < NC) {
            if (SRCF32) { stageB(c + 2, c & 1); stageA(c + 2, c & 1); }
            else        { stageA(c + 2, c & 1); stageB(c + 2, c & 1); }
        }
    }

    // Epilogue. C/D: c_local = (r&3) + 8*(r>>2) + 4*half, t = lane&31.
    float apart = 0.f;
    #pragma unroll
    for (int ts = 0; ts < 2; ++ts) {
        const int t = t0 + tg * 64 + ts * 32 + col;
        if (t >= out_len) continue;
        const float* resf = snf + (size_t)(t + DIL) * in_stride;
        const u16*   resh = snh + (size_t)(t + DIL) * in_stride;
        u16* oh = dst + ((size_t)n * out_len + t) * HID;
        #pragma unroll
        for (int cs = 0; cs < 2; ++cs) {
            #pragma unroll
            for (int g = 0; g < 4; ++g) {
                const int c = c0 + cg * 64 + cs * 32 + g * 8 + half * 4;
                float4 bv = *(const float4*)(bias + c);
                float v0 = acc[cs][ts][g * 4 + 0] + bv.x;
                float v1 = acc[cs][ts][g * 4 + 1] + bv.y;
                float v2 = acc[cs][ts][g * 4 + 2] + bv.z;
                float v3 = acc[cs][ts][g * 4 + 3] + bv.w;
                if (RESID) {
                    if (SRCF32) {
                        float4 r = *(const float4*)(resf + c);
                        v0 = fmaxf(v0, 0.f) + r.x;
                        v1 = fmaxf(v1, 0.f) + r.y;
                        v2 = fmaxf(v2, 0.f) + r.z;
                        v3 = fmaxf(v3, 0.f) + r.w;
                    } else {
                        uint2 r = *(const uint2*)(resh + c);
                        v0 = fmaxf(v0, 0.f) + hlo(r.x);
                        v1 = fmaxf(v1, 0.f) + hhi(r.x);
                        v2 = fmaxf(v2, 0.f) + hlo(r.y);
                        v3 = fmaxf(v3, 0.f) + hhi(r.y);
                    }
                }
                if (ATPM) {
                    float4 wv = *(const float4*)(watpm + c);
                    apart += v0 * wv.x + v1 * wv.y + v2 * wv.z + v3 * wv.w;
                }
                uint2 o; o.x = pk2h(v0, v1); o.y = pk2h(v2, v3);
                *(uint2*)(oh + c) = o;
            }
        }
    }
    if (ATPM) {
        #pragma unroll
        for (int off = 32; off; off >>= 1) apart += __shfl_down(apart, off, 64);
        if (lane == 0) aw[wave] = apart;
        __syncthreads();
        if (tid == 0) atomicAdd(part + n, aw[0] + aw[1] + aw[2] + aw[3]);
    }
}

// ---------------------------------------------------------------------------
// atpm finalize: out[n] = softplus(part[n]/492 + b)
// ---------------------------------------------------------------------------
__global__ void atpm_fin(const float* __restrict__ part,
                         const float* __restrict__ batpm, float* __restrict__ out) {
    int i = threadIdx.x;   // 128
    float tot = part[i] / (float)FINLEN + batpm[0];
    out[i] = fmaxf(tot, 0.f) + log1pf(expf(-fabsf(tot)));
}

// ---------------------------------------------------------------------------
// profile head, sliding-window: out[n][t] = softplus( sum_{ci,k} w[ci][k] h[n][t+k][ci] + b )
// h is fp16 [n][t][256]. Block covers 128 t; thread owns 4 t's x 8-ci subrange.
// grid (4, 128), block 256.
// ---------------------------------------------------------------------------
__global__ __launch_bounds__(256) void prof_kernel(
    const u16* __restrict__ h, const float* __restrict__ wprof,
    const float* __restrict__ bprof, float* __restrict__ out)
{
    __shared__ __attribute__((aligned(16))) float hs[64 * 204];  // 52.2 KB
    __shared__ float red[128 * 8];                               // 4 KB
    const int tid = threadIdx.x;
    const int wave = tid >> 6, lane = tid & 63;
    const int ts = lane & 31, hw = lane >> 5;
    const int cig = wave * 2 + hw;           // 0..7
    const int n = blockIdx.y, t0 = blockIdx.x * 128;
    const u16* hn = h + (size_t)n * FINLEN * HID;
    float acc[4] = {0.f, 0.f, 0.f, 0.f};

    for (int ci0 = 0; ci0 < HID; ci0 += 64) {
        __syncthreads();
        {   // stage rows [t0, t0+203] (clamped) for ci-window, transposed
            const int ci = tid & 63, rg = tid >> 6;
            for (int base = 0; base < 204; base += 16) {
                const int r0 = base + rg * 4;
                if (r0 >= 204) continue;
                float4 v;
                float* vp = (float*)&v;
                #pragma unroll
                for (int j = 0; j < 4; ++j) {
                    int g = t0 + r0 + j; if (g > FINLEN - 1) g = FINLEN - 1;
                    vp[j] = h2f(hn[(size_t)g * HID + ci0 + ci]);
                }
                *(float4*)&hs[ci * 204 + r0] = v;
            }
        }
        __syncthreads();
        for (int ci = 0; ci < 8; ++ci) {
            const int cia = cig * 8 + ci;
            const float4* hrow = (const float4*)&hs[cia * 204];
            const float* wrow = wprof + (size_t)(ci0 + cia) * PROFK;
            float wqf[84];
            #pragma unroll
            for (int q = 0; q < 3; ++q) wqf[q] = 0.f;
            #pragma unroll
            for (int q = 78; q < 84; ++q) wqf[q] = 0.f;
            #pragma unroll
            for (int k = 0; k < PROFK; ++k) wqf[k + 3] = wrow[k];
            #pragma unroll
            for (int m = 0; m < 20; ++m) {
                float4 h4 = hrow[ts + m];
                const float* hp = (const float*)&h4;
                #pragma unroll
                for (int j = 0; j < 4; ++j) {
                    #pragma unroll
                    for (int a = 0; a < 4; ++a) {
                        acc[a] += wqf[4 * m + j - a + 3] * hp[j];
                    }
                }
            }
        }
    }
    #pragma unroll
    for (int a = 0; a < 4; ++a) red[(ts * 4 + a) * 8 + cig] = acc[a];
    __syncthreads();
    if (tid < 128) {
        float s = 0.f;
        #pragma unroll
        for (int c8 = 0; c8 < 8; ++c8) s += red[tid * 8 + c8];
        const int t = t0 + tid;
        if (t < PROFLEN) {
            float v = s + bprof[0];
            out[(size_t)n * PROFLEN + t] = fmaxf(v, 0.f) + log1pf(expf(-fabsf(v)));
        }
    }
}

// ---------------------------------------------------------------------------
extern "C" void kernel_launch(void* const* d_in, const int* in_sizes, int n_in,
                              void* d_out, int out_size, void* d_ws, size_t ws_size,
                              hipStream_t stream) {
    const float* x     = (const float*)d_in[0];
    const float* wproj = (const float*)d_in[4];
    const float* bproj = (const float*)d_in[5];
    const float* wdil  = (const float*)d_in[6];
    const float* bdil  = (const float*)d_in[7];
    const float* wprof = (const float*)d_in[8];
    const float* bprof = (const float*)d_in[9];
    const float* watpm = (const float*)d_in[10];
    const float* batpm = (const float*)d_in[11];
    float* outAtpm = (float*)d_out;
    float* outProf = outAtpm + NPEAKS;

    // ws layout (~134.2 MB of the >=262 MB workspace), all fp16 activations:
    //   hA @ 0          : 65,536,000 B
    //   hB @ 65536000   : 65,536,000 B
    //   wpf @ 131072000 : 327,680 B (proj weights fp16 frag-ordered)
    //   wslot @ 131399680 : 7 x 393,216 B (all dilated-layer weights, repacked upfront)
    //   part @ 134152192 : 512 B (atpm partials)
    char* ws = (char*)d_ws;
    u16* hA    = (u16*)ws;
    u16* hB    = (u16*)(ws + 65536000);
    u16* wpf   = (u16*)(ws + 131072000);
    u16* wslot = (u16*)(ws + 131399680);
    float* part = (float*)(ws + 134152192);

    // all weight repacks upfront (no mid-stream launches, no rotating-buffer dep)
    conv_wproj<<<(MOTIF * HID + 255) / 256, 256, 0, stream>>>(wproj, wpf);
    conv_wdil_all<<<dim3(768, DEPTHN), 256, 0, stream>>>(wdil, wslot, part);

    // projection: x fp32 (K=640, chunks of 32ci, NC=20) -> hA fp16 [n][t][c]
    mfma_gemm<1, MOTIF, 32, 0, true, false, false><<<dim3(8, 2, NPEAKS), 256, 0, stream>>>(
        x, PEAK, MOTIF, wpf, bproj, hA, PEAK, nullptr, nullptr);

    // dilated tower: chunks of 16ci, NC=16
    #define LAYER(i, DIL, SRC, DST, INL, OUTL, TT)                                              \
        mfma_gemm<3, HID, 16, DIL, false, true, false><<<dim3(TT, 2, NPEAKS), 256, 0, stream>>>( \
            SRC, INL, HID, wslot + (size_t)(i) * (3 * HID * HID),                               \
            bdil + (size_t)(i) * HID, DST, OUTL, nullptr, nullptr);
    LAYER(0,   2, hA, hB, 1000, 996, 8)
    LAYER(1,   4, hB, hA,  996, 988, 8)
    LAYER(2,   8, hA, hB,  988, 972, 8)
    LAYER(3,  16, hB, hA,  972, 940, 8)
    LAYER(4,  32, hA, hB,  940, 876, 7)
    LAYER(5,  64, hB, hA,  876, 748, 6)
    #undef LAYER
    // layer 6 with fused atpm partial accumulation (part zeroed in the repack)
    mfma_gemm<3, HID, 16, 128, false, true, true><<<dim3(4, 2, NPEAKS), 256, 0, stream>>>(
        hA, 748, HID, wslot + (size_t)6 * (3 * HID * HID), bdil + (size_t)6 * HID,
        hB, 492, watpm, part);

    atpm_fin<<<1, 128, 0, stream>>>(part, batpm, outAtpm);
    prof_kernel<<<dim3(4, NPEAKS), 256, 0, stream>>>(hB, wprof, bprof, outProf);
}